// Round 2
// baseline (211.723 us; speedup 1.0000x reference)
//
#include <hip/hip_runtime.h>
#include <math.h>

// Problem constants (from reference)
#define NQ 32768   // query points (pos1)
#define MC 8192    // source points (pos2)
#define CC 128     // channels
#define EPS_BN 1e-5f
#define EPS_D  1e-8

#define DBL_BIG 1e300
#define IDX_BIG 0x7fffffff

// KNN config (R8: wave-uniform candidate stream in SGPRs via s_load;
// no LDS/barriers in main loop; 1 query per lane; 1024 scan blocks)
#define QB  64          // queries per block (1 per lane)
#define TB  512         // threads per block (8 waves)
#define NW  8           // waves per block
#define HM  (MC / 2)    // half of M per block = 4096
#define SLCW (HM / NW)  // per-wave candidate slice = 512
#define KMASK 0xFFFFE000u   // keep sign+exp+10 mantissa bits
#define IMASK 0x1FFFu       // 13-bit index (M=8192)
#define NSURV 64            // survivors per query (2 halves x 8 waves x 4)
#define KNN_B ((NQ / QB) * 2)   // 1024 scan blocks
#define GEMM_B (NQ / 64)        // 512
#define NGRP 8                  // stats atomic groups (2048 addresses)

typedef __attribute__((ext_vector_type(8))) short bf16x8;   // 8 bf16 (4 VGPRs)
typedef __attribute__((ext_vector_type(4))) float floatx4;  // MFMA accumulator
typedef unsigned short ushort_t;

// RNE fp32 -> bf16 pair packed in u32 (lo = a, hi = b)
__device__ __forceinline__ unsigned bf16pair(float a, float b) {
    unsigned ua = __float_as_uint(a); ua = (ua + 0x7FFFu + ((ua >> 16) & 1u)) >> 16;
    unsigned ub = __float_as_uint(b); ub = (ub + 0x7FFFu + ((ub >> 16) & 1u)) >> 16;
    return ua | (ub << 16);
}
__device__ __forceinline__ ushort_t bf16one(float a) {
    unsigned ua = __float_as_uint(a);
    return (ushort_t)((ua + 0x7FFFu + ((ua >> 16) & 1u)) >> 16);
}
// unpack u32 = (lo bf16, hi bf16) -> 2 fp32
__device__ __forceinline__ float bflo(unsigned u) { return __uint_as_float(u << 16); }
__device__ __forceinline__ float bfhi(unsigned u) { return __uint_as_float(u & 0xFFFF0000u); }

// Branchless insert of x into ascending top-4 (k0<=k1<=k2<=k3):
// 1x v_min_f32 + 3x v_med3_f32.
__device__ __forceinline__ void ins4(float& k0, float& k1, float& k2, float& k3, float x) {
    const float n0 = fminf(k0, x);
    const float n1 = __builtin_amdgcn_fmed3f(k0, k1, x);
    const float n2 = __builtin_amdgcn_fmed3f(k1, k2, x);
    const float n3 = __builtin_amdgcn_fmed3f(k2, k3, x);
    k0 = n0; k1 = n1; k2 = n2; k3 = n3;
}

// Sortable float key from prepacked candidate c = {x, y, z, 0.5|c|^2}:
// t = 0.5*d^2 (+ ~1e-6 cancellation noise), mantissa truncated to 10 bits,
// candidate index in low 13 bits. Each VALU op reads at most 1 SGPR
// (candidate components are wave-uniform -> SGPRs).
__device__ __forceinline__ float mkk(float nx, float ny, float nz, float hp,
                                     float4 c, unsigned j) {
    float t = c.w + hp;                 // v_add_f32 t, s_hc, v_hp
    t = fmaf(nz, c.z, t);               // v_fmac    t, s_cz, v_nz
    t = fmaf(ny, c.y, t);
    t = fmaf(nx, c.x, t);
    return __uint_as_float((__float_as_uint(t) & KMASK) | j);  // and(lit) + or(sgpr)
}

// ---------------------------------------------------------------------------
// Pack pos2 -> {x, y, z, 0.5|c|^2} (16 B/cand, 128 KB, L2-resident).
// Must run before knn scan blocks (separate launch for ordering).
// ---------------------------------------------------------------------------
__global__ __launch_bounds__(TB) void pack_kernel(const float* __restrict__ pos2,
                                                  float4* __restrict__ pos2pk) {
    const int c0 = blockIdx.x * (MC / 8);
#pragma unroll
    for (int c = c0 + threadIdx.x; c < c0 + MC / 8; c += TB) {
        const float x = pos2[c * 3 + 0];
        const float y = pos2[c * 3 + 1];
        const float z = pos2[c * 3 + 2];
        float4 v;
        v.x = x; v.y = y; v.z = z;
        v.w = 0.5f * fmaf(x, x, fmaf(y, y, z * z));
        pos2pk[c] = v;
    }
}

// ---------------------------------------------------------------------------
// KNN scan + piggy-backed weight conversion + stats zero.
// Blocks [0, KNN_B): 64 queries (1/lane) x half of M; 8 waves each scan a
//   512-cand slice streamed through SGPRs (s_load_dwordx16 from pos2pk).
//   No LDS, no barriers in the main loop. Top-4 via med3 sorted-insert.
//   Survivor dump via small LDS buffer (stride-33 pad, conflict-free).
// Blocks [KNN_B, KNN_B+8): convert W0/W1/W2 fp32 -> bf16; block KNN_B also
//   zeroes the 3 layers' stats accumulators.
// ---------------------------------------------------------------------------
__global__ __launch_bounds__(TB) void knn_kernel(const float* __restrict__ pos1,
                                                 const float4* __restrict__ pos2pk,
                                                 unsigned* __restrict__ skeys,
                                                 const float* __restrict__ W0,
                                                 const float* __restrict__ W1,
                                                 const float* __restrict__ W2,
                                                 ushort_t* __restrict__ Wbf,
                                                 float* __restrict__ stats) {
    __shared__ unsigned skl[QB][33];   // 8.4 KB survivor staging

    if (blockIdx.x >= KNN_B) {                 // ---- prep blocks ----
        const int pb = blockIdx.x - KNN_B;     // 0..7
        const int f = pb * TB + threadIdx.x;   // float4 index within a layer
        const float* Ws[3] = {W0, W1, W2};
#pragma unroll
        for (int l = 0; l < 3; ++l) {
            const float4 v = ((const float4*)Ws[l])[f];
            unsigned* dst = (unsigned*)(Wbf + (size_t)l * CC * CC);
            dst[f * 2 + 0] = bf16pair(v.x, v.y);
            dst[f * 2 + 1] = bf16pair(v.z, v.w);
        }
        if (pb == 0)
            for (int i = threadIdx.x; i < 3 * NGRP * 256; i += TB) stats[i] = 0.f;
        return;
    }

    const int half = blockIdx.x & 1;
    const int bq   = blockIdx.x >> 1;
    const int ln = threadIdx.x & 63;   // lane = query owner
    // force wave id uniform so the candidate address scalarizes to s_load
    const int wvu = __builtin_amdgcn_readfirstlane((int)(threadIdx.x >> 6));
    const int q  = bq * QB + ln;

    const float px = pos1[q * 3 + 0];
    const float py = pos1[q * 3 + 1];
    const float pz = pos1[q * 3 + 2];
    const float nx = -px, ny = -py, nz = -pz;
    const float hp = 0.5f * fmaf(px, px, fmaf(py, py, pz * pz));

    const int jb = half * HM + wvu * SLCW;
    const float4* cp = pos2pk + jb;

    const float KINIT = __uint_as_float(0x7F000000u);   // large finite sentinel
    float k0 = KINIT, k1 = KINIT, k2 = KINIT, k3 = KINIT;

#pragma unroll 4
    for (int gi = 0; gi < SLCW / 4; ++gi) {
        const float4 c0 = cp[gi * 4 + 0];   // wave-uniform -> s_load_dwordx16
        const float4 c1 = cp[gi * 4 + 1];
        const float4 c2 = cp[gi * 4 + 2];
        const float4 c3 = cp[gi * 4 + 3];
        const unsigned j0 = (unsigned)(jb + gi * 4);
        ins4(k0, k1, k2, k3, mkk(nx, ny, nz, hp, c0, j0 + 0));
        ins4(k0, k1, k2, k3, mkk(nx, ny, nz, hp, c1, j0 + 1));
        ins4(k0, k1, k2, k3, mkk(nx, ny, nz, hp, c2, j0 + 2));
        ins4(k0, k1, k2, k3, mkk(nx, ny, nz, hp, c3, j0 + 3));
    }

    skl[ln][wvu * 4 + 0] = __float_as_uint(k0);
    skl[ln][wvu * 4 + 1] = __float_as_uint(k1);
    skl[ln][wvu * 4 + 2] = __float_as_uint(k2);
    skl[ln][wvu * 4 + 3] = __float_as_uint(k3);
    __syncthreads();

    // coalesced dump: query q's survivors at skeys[q*64 + half*32 + slot]
#pragma unroll
    for (int t = threadIdx.x * 4; t < threadIdx.x * 4 + 4; ++t) {
        const int ql = t >> 5, slot = t & 31;
        skeys[(size_t)(bq * QB + ql) * NSURV + half * 32 + slot] = skl[ql][slot];
    }
}

// ---------------------------------------------------------------------------
// bf16-MFMA fused layer GEMM: Y = Xin @ W^T + bias (fp32 accumulate).
//   MODE 0: prologue re-ranks this block's own 64 queries (fp64 exact) from
//           skeys, then Xin = interp(feat2(fp32), idx, w). Y out: bf16.
//   MODE 1: prologue reduces statsIn[8][256] -> BN scale/shift in LDS, then
//           Xin = relu(Xbf16 * sc[c] + sh[c]). Y out: bf16.
// Y is stored bf16 (halves inter-layer HBM traffic; next stage re-rounds to
// bf16 anyway, extra error ~2e-3/layer). Stats stay fp32 from accumulators.
// Epilogue stats -> 8-group atomicAdd (2048 addresses, zeroed by knn prep).
// grid = 512, block = 256.
// ---------------------------------------------------------------------------
template <int MODE>
__global__ __launch_bounds__(256) void gemm_mfma(const void* __restrict__ Xsrc_,
                                                 const unsigned* __restrict__ skeys,
                                                 const float* __restrict__ pos1,
                                                 const float* __restrict__ pos2,
                                                 const float* __restrict__ statsIn,
                                                 const float* __restrict__ gIn,
                                                 const float* __restrict__ beIn,
                                                 const ushort_t* __restrict__ Wb,
                                                 const float* __restrict__ bias,
                                                 ushort_t* __restrict__ Y,
                                                 float* __restrict__ statsOut) {
    __shared__ __align__(16) short xa[64][136];    // 64 rows x 128 k bf16
    __shared__ __align__(16) short wb[128][136];   // 128 co x 128 k bf16
    __shared__ float blk_s[CC], blk_q[CC];         // epilogue stat accumulators
    __shared__ float sc_l[CC], sh_l[CC];           // MODE 1 BN scale/shift

    const int row0 = blockIdx.x * 64;

    // ---- X tile staging (+ fused transform) ----
    if constexpr (MODE == 0) {
        const float* feat2 = (const float*)Xsrc_;
        __shared__ int   lidx[QB][3];
        __shared__ float lw[QB][3];
        {   // exact fp64 re-rank of this block's 64 queries; 4 thr/query
            double* rrd = (double*)&xa[0][0];   // [64][4][3] = 6144 B scratch
            int*    rri = (int*)&wb[0][0];      // [64][4][3] = 3072 B scratch
            const int ql = threadIdx.x >> 2;
            const int pp = threadIdx.x & 3;
            const int qg = row0 + ql;
            const double qx = (double)pos1[qg * 3 + 0];
            const double qy = (double)pos1[qg * 3 + 1];
            const double qz = (double)pos1[qg * 3 + 2];
            double b0 = DBL_BIG, b1 = DBL_BIG, b2 = DBL_BIG;
            int    j0 = IDX_BIG, j1 = IDX_BIG, j2 = IDX_BIG;
            const uint4* kp = (const uint4*)(skeys + (size_t)qg * NSURV + pp * 16);
#pragma unroll
            for (int gi = 0; gi < 4; ++gi) {
                const uint4 kk = kp[gi];
                const unsigned ks[4] = {kk.x, kk.y, kk.z, kk.w};
#pragma unroll
                for (int u = 0; u < 4; ++u) {
                    const int id = (int)(ks[u] & IMASK);
                    const double x = (double)pos2[id * 3 + 0];
                    const double y = (double)pos2[id * 3 + 1];
                    const double z = (double)pos2[id * 3 + 2];
                    const double ax = qx - x, ay = qy - y, az = qz - z;
                    const double d = ax * ax + ay * ay + az * az;
                    const bool l2 = (d < b2) || (d == b2 && id < j2);
                    if (l2) {
                        const bool l1 = (d < b1) || (d == b1 && id < j1);
                        const bool l0 = (d < b0) || (d == b0 && id < j0);
                        b2 = l1 ? b1 : d;              j2 = l1 ? j1 : id;
                        b1 = l1 ? (l0 ? b0 : d) : b1;  j1 = l1 ? (l0 ? j0 : id) : j1;
                        b0 = l0 ? d : b0;              j0 = l0 ? id : j0;
                    }
                }
            }
            const int base = (ql * 4 + pp) * 3;
            rrd[base + 0] = b0; rri[base + 0] = j0;
            rrd[base + 1] = b1; rri[base + 1] = j1;
            rrd[base + 2] = b2; rri[base + 2] = j2;
            __syncthreads();
            if (threadIdx.x < QB) {
                const int qq = threadIdx.x;
                double c0 = DBL_BIG, c1 = DBL_BIG, c2 = DBL_BIG;
                int    i0 = IDX_BIG, i1 = IDX_BIG, i2 = IDX_BIG;
#pragma unroll
                for (int s = 0; s < 12; ++s) {
                    const double d = rrd[qq * 12 + s];
                    const int   id = rri[qq * 12 + s];
                    const bool l2 = (d < c2) || (d == c2 && id < i2);
                    if (l2) {
                        const bool l1 = (d < c1) || (d == c1 && id < i1);
                        const bool l0 = (d < c0) || (d == c0 && id < i0);
                        c2 = l1 ? c1 : d;              i2 = l1 ? i1 : id;
                        c1 = l1 ? (l0 ? c0 : d) : c1;  i1 = l1 ? (l0 ? i0 : id) : i1;
                        c0 = l0 ? d : c0;              i0 = l0 ? id : i0;
                    }
                }
                const double r0 = 1.0 / (c0 + EPS_D);
                const double r1 = 1.0 / (c1 + EPS_D);
                const double r2 = 1.0 / (c2 + EPS_D);
                const double inv = 1.0 / (r0 + r1 + r2);
                lidx[qq][0] = i0; lidx[qq][1] = i1; lidx[qq][2] = i2;
                lw[qq][0] = (float)(r0 * inv);
                lw[qq][1] = (float)(r1 * inv);
                lw[qq][2] = (float)(r2 * inv);
            }
            __syncthreads();
        }
        if (threadIdx.x < CC) { blk_s[threadIdx.x] = 0.f; blk_q[threadIdx.x] = 0.f; }
#pragma unroll
        for (int e = threadIdx.x; e < 64 * 32; e += 256) {
            const int r = e >> 5, c4 = e & 31;
            const int i0 = lidx[r][0], i1 = lidx[r][1], i2 = lidx[r][2];
            const float w0 = lw[r][0], w1 = lw[r][1], w2 = lw[r][2];
            const float4 f0 = *(const float4*)&feat2[(size_t)i0 * CC + c4 * 4];
            const float4 f1 = *(const float4*)&feat2[(size_t)i1 * CC + c4 * 4];
            const float4 f2 = *(const float4*)&feat2[(size_t)i2 * CC + c4 * 4];
            float4 v;
            v.x = w0 * f0.x + w1 * f1.x + w2 * f2.x;
            v.y = w0 * f0.y + w1 * f1.y + w2 * f2.y;
            v.z = w0 * f0.z + w1 * f1.z + w2 * f2.z;
            v.w = w0 * f0.w + w1 * f1.w + w2 * f2.w;
            unsigned* dst = (unsigned*)&xa[r][0];
            dst[c4 * 2 + 0] = bf16pair(v.x, v.y);
            dst[c4 * 2 + 1] = bf16pair(v.z, v.w);
        }
    } else {
        const ushort_t* Xbf = (const ushort_t*)Xsrc_;
        // ---- BN prologue: reduce 8-group stats -> scale/shift in LDS ----
        if (threadIdx.x < CC) {
            const int c = threadIdx.x;
            float s = 0.f, q = 0.f;
#pragma unroll
            for (int gr = 0; gr < NGRP; ++gr) {
                s += statsIn[gr * 256 + c];
                q += statsIn[gr * 256 + CC + c];
            }
            const float m = s * (1.f / (float)NQ);
            const float v = fmaf(-m, m, q * (1.f / (float)NQ));
            const float rstd = rsqrtf(v + EPS_BN);
            const float scl = gIn[c] * rstd;
            sc_l[c] = scl;
            sh_l[c] = fmaf(-m, scl, beIn[c]);
            blk_s[c] = 0.f; blk_q[c] = 0.f;
        }
        __syncthreads();
        // X staging: uint4 = 8 bf16 per iter, 4 iters/thread
#pragma unroll
        for (int e = threadIdx.x; e < 64 * 16; e += 256) {
            const int r = e >> 4, c8 = e & 15;
            const uint4 u = *(const uint4*)&Xbf[(size_t)(row0 + r) * CC + c8 * 8];
            const float4 s0 = *(const float4*)&sc_l[c8 * 8];
            const float4 s1 = *(const float4*)&sc_l[c8 * 8 + 4];
            const float4 h0 = *(const float4*)&sh_l[c8 * 8];
            const float4 h1 = *(const float4*)&sh_l[c8 * 8 + 4];
            const float v0 = fmaxf(fmaf(bflo(u.x), s0.x, h0.x), 0.f);
            const float v1 = fmaxf(fmaf(bfhi(u.x), s0.y, h0.y), 0.f);
            const float v2 = fmaxf(fmaf(bflo(u.y), s0.z, h0.z), 0.f);
            const float v3 = fmaxf(fmaf(bfhi(u.y), s0.w, h0.w), 0.f);
            const float v4 = fmaxf(fmaf(bflo(u.z), s1.x, h1.x), 0.f);
            const float v5 = fmaxf(fmaf(bfhi(u.z), s1.y, h1.y), 0.f);
            const float v6 = fmaxf(fmaf(bflo(u.w), s1.z, h1.z), 0.f);
            const float v7 = fmaxf(fmaf(bfhi(u.w), s1.w, h1.w), 0.f);
            uint4 o;
            o.x = bf16pair(v0, v1); o.y = bf16pair(v2, v3);
            o.z = bf16pair(v4, v5); o.w = bf16pair(v6, v7);
            *(uint4*)&xa[r][c8 * 8] = o;
        }
    }
    // ---- W tile staging: pre-converted bf16, 16B copies ----
#pragma unroll
    for (int e = threadIdx.x; e < 128 * 16; e += 256) {
        const int co = e >> 4, seg = e & 15;
        *(float4*)&wb[co][seg * 8] = *(const float4*)&Wb[(size_t)co * CC + seg * 8];
    }
    __syncthreads();

    const int lane = threadIdx.x & 63;
    const int wv = threadIdx.x >> 6;     // wave -> rows 16*wv..+15
    const int nn = lane & 15;
    const int quad = lane >> 4;

    floatx4 acc[8] = {};

    const short* arow = &xa[wv * 16 + nn][0];
#pragma unroll
    for (int ks = 0; ks < 4; ++ks) {
        const bf16x8 a = *(const bf16x8*)(arow + ks * 32 + quad * 8);
#pragma unroll
        for (int ct = 0; ct < 8; ++ct) {
            const bf16x8 b = *(const bf16x8*)(&wb[ct * 16 + nn][0] + ks * 32 + quad * 8);
            acc[ct] = __builtin_amdgcn_mfma_f32_16x16x32_bf16(a, b, acc[ct], 0, 0, 0);
        }
    }

    // ---- epilogue: bias, bf16 Y store, column stats (fp32) ----
#pragma unroll
    for (int ct = 0; ct < 8; ++ct) {
        const float bv = bias[ct * 16 + nn];
        float s = 0.f, qv = 0.f;
#pragma unroll
        for (int r = 0; r < 4; ++r) {
            acc[ct][r] += bv;
            s += acc[ct][r];
            qv = fmaf(acc[ct][r], acc[ct][r], qv);
        }
#pragma unroll
        for (int r = 0; r < 4; ++r)
            Y[(size_t)(row0 + wv * 16 + quad * 4 + r) * CC + ct * 16 + nn] = bf16one(acc[ct][r]);
        s += __shfl_xor(s, 16, 64); s += __shfl_xor(s, 32, 64);
        qv += __shfl_xor(qv, 16, 64); qv += __shfl_xor(qv, 32, 64);
        if (quad == 0) {
            atomicAdd(&blk_s[ct * 16 + nn], s);
            atomicAdd(&blk_q[ct * 16 + nn], qv);
        }
    }
    __syncthreads();
    // 8-group global stats: low-contention atomicAdd (2048 addresses)
    {
        const int ch = threadIdx.x;
        const float v = (ch < CC) ? blk_s[ch] : blk_q[ch - CC];
        atomicAdd(&statsOut[(blockIdx.x & (NGRP - 1)) * 256 + ch], v);
    }
}

// ---------------------------------------------------------------------------
// Final BN + ReLU with in-kernel stats reduce; bf16 in, fp32 out.
// grid = 512 x 256; each thread handles 4 x 8 elements.
// ---------------------------------------------------------------------------
__global__ __launch_bounds__(256) void bn_final(const ushort_t* __restrict__ Y,
                                                const float* __restrict__ statsIn,
                                                const float* __restrict__ g,
                                                const float* __restrict__ be,
                                                float* __restrict__ out) {
    __shared__ float sc_l[CC], sh_l[CC];
    if (threadIdx.x < CC) {
        const int c = threadIdx.x;
        float s = 0.f, q = 0.f;
#pragma unroll
        for (int gr = 0; gr < NGRP; ++gr) {
            s += statsIn[gr * 256 + c];
            q += statsIn[gr * 256 + CC + c];
        }
        const float m = s * (1.f / (float)NQ);
        const float v = fmaf(-m, m, q * (1.f / (float)NQ));
        const float rstd = rsqrtf(v + EPS_BN);
        const float scl = g[c] * rstd;
        sc_l[c] = scl;
        sh_l[c] = fmaf(-m, scl, be[c]);
    }
    __syncthreads();
    const int base = blockIdx.x * 1024 + threadIdx.x;   // 8-col group index
#pragma unroll
    for (int it = 0; it < 4; ++it) {
        const int i8 = base + it * 256;
        const int c8 = (i8 & 15) * 8;
        const uint4 u = *(const uint4*)&Y[(size_t)i8 * 8];
        const float4 s0 = *(const float4*)&sc_l[c8];
        const float4 s1 = *(const float4*)&sc_l[c8 + 4];
        const float4 h0 = *(const float4*)&sh_l[c8];
        const float4 h1 = *(const float4*)&sh_l[c8 + 4];
        float4 o0, o1;
        o0.x = fmaxf(fmaf(bflo(u.x), s0.x, h0.x), 0.f);
        o0.y = fmaxf(fmaf(bfhi(u.x), s0.y, h0.y), 0.f);
        o0.z = fmaxf(fmaf(bflo(u.y), s0.z, h0.z), 0.f);
        o0.w = fmaxf(fmaf(bfhi(u.y), s0.w, h0.w), 0.f);
        o1.x = fmaxf(fmaf(bflo(u.z), s1.x, h1.x), 0.f);
        o1.y = fmaxf(fmaf(bfhi(u.z), s1.y, h1.y), 0.f);
        o1.z = fmaxf(fmaf(bflo(u.w), s1.z, h1.z), 0.f);
        o1.w = fmaxf(fmaf(bfhi(u.w), s1.w, h1.w), 0.f);
        ((float4*)out)[i8 * 2 + 0] = o0;
        ((float4*)out)[i8 * 2 + 1] = o1;
    }
}

// ---------------------------------------------------------------------------
extern "C" void kernel_launch(void* const* d_in, const int* in_sizes, int n_in,
                              void* d_out, int out_size, void* d_ws, size_t ws_size,
                              hipStream_t stream) {
    (void)in_sizes; (void)n_in; (void)out_size; (void)ws_size;

    const float* pos1  = (const float*)d_in[0];
    const float* pos2  = (const float*)d_in[1];
    const float* feat2 = (const float*)d_in[2];
    const float* Wl[3]  = {(const float*)d_in[3], (const float*)d_in[7],  (const float*)d_in[11]};
    const float* bl[3]  = {(const float*)d_in[4], (const float*)d_in[8],  (const float*)d_in[12]};
    const float* gl[3]  = {(const float*)d_in[5], (const float*)d_in[9],  (const float*)d_in[13]};
    const float* bel[3] = {(const float*)d_in[6], (const float*)d_in[10], (const float*)d_in[14]};

    // Workspace layout
    float* ws = (float*)d_ws;
    ushort_t* B0 = (ushort_t*)ws;                   // NQ*CC bf16 (8 MB)
    ushort_t* B1 = B0 + (size_t)NQ * CC;            // NQ*CC bf16 (8 MB)
    unsigned* skeys = (unsigned*)(B1 + (size_t)NQ * CC);   // NQ*64 u32 (8 MB)
    float* stats = (float*)(skeys + (size_t)NQ * NSURV);   // 3*NGRP*256 floats
    ushort_t* Wbf = (ushort_t*)(stats + 3 * NGRP * 256);   // 3*16384 bf16
    float4* pos2pk = (float4*)(Wbf + 3 * CC * CC);         // MC*16 B (128 KB)

    float* st0 = stats + 0 * NGRP * 256;
    float* st1 = stats + 1 * NGRP * 256;
    float* st2 = stats + 2 * NGRP * 256;

    // 0: pack pos2 -> {x,y,z,0.5|c|^2} (must precede knn scan)
    pack_kernel<<<8, TB, 0, stream>>>(pos2, pos2pk);
    // 1: KNN scan (SGPR candidate stream) + W bf16 prep + stats zero
    knn_kernel<<<KNN_B + 8, TB, 0, stream>>>(pos1, pos2pk, skeys,
                                             Wl[0], Wl[1], Wl[2], Wbf, stats);
    // 2: layer 0 (rerank + interp fused) -> B0 (bf16), st0
    gemm_mfma<0><<<GEMM_B, 256, 0, stream>>>(feat2, skeys, pos1, pos2,
                                             nullptr, nullptr, nullptr,
                                             Wbf + 0 * CC * CC, bl[0], B0, st0);
    // 3: layer 1 (stats-reduce + BN fused) -> B1 (bf16), st1
    gemm_mfma<1><<<GEMM_B, 256, 0, stream>>>(B0, nullptr, nullptr, nullptr,
                                             st0, gl[0], bel[0],
                                             Wbf + 1 * CC * CC, bl[1], B1, st1);
    // 4: layer 2 -> B0 (bf16), st2
    gemm_mfma<1><<<GEMM_B, 256, 0, stream>>>(B1, nullptr, nullptr, nullptr,
                                             st1, gl[1], bel[1],
                                             Wbf + 2 * CC * CC, bl[2], B0, st2);
    // 5: final BN+ReLU (stats-reduce fused) -> out (fp32)
    bn_final<<<GEMM_B, 256, 0, stream>>>(B0, st2, gl[2], bel[2], (float*)d_out);
}

// Round 3
// 203.280 us; speedup vs baseline: 1.0415x; 1.0415x over previous
//
#include <hip/hip_runtime.h>
#include <math.h>

// Problem constants (from reference)
#define NQ 32768   // query points (pos1)
#define MC 8192    // source points (pos2)
#define CC 128     // channels
#define EPS_BN 1e-5f
#define EPS_D  1e-8

#define DBL_BIG 1e300
#define IDX_BIG 0x7fffffff

// KNN config (R9: SGPR candidate stream, 2-deep SW pipeline, bfi key pack,
// top-3/slice, 256-thread blocks, 4 M-pieces)
#define QB  64          // queries per block (1 per lane)
#define TB  256         // threads per block (4 waves)
#define NW  4           // waves per block
#define PCE (MC / 4)    // piece of M per block = 2048
#define SLCW (PCE / NW) // per-wave candidate slice = 512
#define NG  (SLCW / 4)  // 4-candidate groups per wave = 128
#define KMASK 0xFFFFE000u   // keep sign+exp+10 mantissa bits
#define IMASK 0x1FFFu       // 13-bit index (M=8192)
#define NSURV 48            // survivors per query (4 pieces x 4 waves x 3)
#define KNN_B ((NQ / QB) * 4)   // 2048 scan blocks
#define GEMM_B (NQ / 64)        // 512
#define NGRP 8                  // stats atomic groups (2048 addresses)

typedef __attribute__((ext_vector_type(8))) short bf16x8;   // 8 bf16 (4 VGPRs)
typedef __attribute__((ext_vector_type(4))) float floatx4;  // MFMA accumulator
typedef unsigned short ushort_t;

// RNE fp32 -> bf16 pair packed in u32 (lo = a, hi = b)
__device__ __forceinline__ unsigned bf16pair(float a, float b) {
    unsigned ua = __float_as_uint(a); ua = (ua + 0x7FFFu + ((ua >> 16) & 1u)) >> 16;
    unsigned ub = __float_as_uint(b); ub = (ub + 0x7FFFu + ((ub >> 16) & 1u)) >> 16;
    return ua | (ub << 16);
}
__device__ __forceinline__ ushort_t bf16one(float a) {
    unsigned ua = __float_as_uint(a);
    return (ushort_t)((ua + 0x7FFFu + ((ua >> 16) & 1u)) >> 16);
}
// unpack u32 = (lo bf16, hi bf16) -> 2 fp32
__device__ __forceinline__ float bflo(unsigned u) { return __uint_as_float(u << 16); }
__device__ __forceinline__ float bfhi(unsigned u) { return __uint_as_float(u & 0xFFFF0000u); }

// Branchless insert of x into ascending top-3 (k0<=k1<=k2):
// 1x v_min_f32 + 2x v_med3_f32. (min(a,x), med3(a,b,x), med3(b,c,x)).
__device__ __forceinline__ void ins3(float& k0, float& k1, float& k2, float x) {
    const float n0 = fminf(k0, x);
    const float n1 = __builtin_amdgcn_fmed3f(k0, k1, x);
    const float n2 = __builtin_amdgcn_fmed3f(k1, k2, x);
    k0 = n0; k1 = n1; k2 = n2;
}

// Sortable float key from prepacked candidate c = {x, y, z, 0.5|c|^2}:
// t = 0.5*d^2 (+ ~1e-6 cancellation noise); low 13 mantissa bits replaced by
// the candidate index via bfi ((t & KMASK) | (j & ~KMASK) -> v_bfi_b32).
// Each VALU op reads at most 1 SGPR (candidate components are wave-uniform).
__device__ __forceinline__ float mkk(float nx, float ny, float nz, float hp,
                                     float4 c, unsigned j) {
    float t = c.w + hp;                 // v_add_f32 t, s_hc, v_hp
    t = fmaf(nz, c.z, t);               // v_fmac    t, s_cz, v_nz
    t = fmaf(ny, c.y, t);
    t = fmaf(nx, c.x, t);
    const unsigned u = (__float_as_uint(t) & KMASK) | (j & ~KMASK);  // v_bfi_b32
    return __uint_as_float(u);
}

// ---------------------------------------------------------------------------
// Pack pos2 -> {x, y, z, 0.5|c|^2} (16 B/cand, 128 KB, L2-resident) + 4-entry
// pad (prefetch overshoot guard). Must run before knn scan blocks.
// ---------------------------------------------------------------------------
__global__ __launch_bounds__(TB) void pack_kernel(const float* __restrict__ pos2,
                                                  float4* __restrict__ pos2pk) {
    const int c0 = blockIdx.x * (MC / 8);
#pragma unroll
    for (int c = c0 + threadIdx.x; c < c0 + MC / 8; c += TB) {
        const float x = pos2[c * 3 + 0];
        const float y = pos2[c * 3 + 1];
        const float z = pos2[c * 3 + 2];
        float4 v;
        v.x = x; v.y = y; v.z = z;
        v.w = 0.5f * fmaf(x, x, fmaf(y, y, z * z));
        pos2pk[c] = v;
    }
    if (blockIdx.x == 0 && threadIdx.x < 4) {
        float4 zf; zf.x = 0.f; zf.y = 0.f; zf.z = 0.f; zf.w = 0.f;
        pos2pk[MC + threadIdx.x] = zf;   // overshoot pad
    }
}

// ---------------------------------------------------------------------------
// KNN scan + piggy-backed weight conversion + stats zero.
// Blocks [0, KNN_B): 64 queries (1/lane) x one quarter of M; 4 waves each
//   scan a 512-cand slice streamed through SGPRs with an explicit 2-deep
//   software pipeline (s_load of group g+1 issued before consuming group g).
//   No LDS, no barriers in the main loop. Top-3/slice via med3 sorted-insert.
// Blocks [KNN_B, KNN_B+16): convert W0/W1/W2 fp32 -> bf16; block KNN_B also
//   zeroes the 3 layers' stats accumulators.
// ---------------------------------------------------------------------------
__global__ __launch_bounds__(TB) void knn_kernel(const float* __restrict__ pos1,
                                                 const float4* __restrict__ pos2pk,
                                                 unsigned* __restrict__ skeys,
                                                 const float* __restrict__ W0,
                                                 const float* __restrict__ W1,
                                                 const float* __restrict__ W2,
                                                 ushort_t* __restrict__ Wbf,
                                                 float* __restrict__ stats) {
    __shared__ unsigned skl[QB][13];   // 3.3 KB survivor staging (13: conflict-free)

    if (blockIdx.x >= KNN_B) {                 // ---- prep blocks ----
        const int pb = blockIdx.x - KNN_B;     // 0..15
        const int f = pb * TB + threadIdx.x;   // float4 index within a layer
        const float* Ws[3] = {W0, W1, W2};
#pragma unroll
        for (int l = 0; l < 3; ++l) {
            const float4 v = ((const float4*)Ws[l])[f];
            unsigned* dst = (unsigned*)(Wbf + (size_t)l * CC * CC);
            dst[f * 2 + 0] = bf16pair(v.x, v.y);
            dst[f * 2 + 1] = bf16pair(v.z, v.w);
        }
        if (pb == 0)
            for (int i = threadIdx.x; i < 3 * NGRP * 256; i += TB) stats[i] = 0.f;
        return;
    }

    const int piece = blockIdx.x & 3;
    const int bq    = blockIdx.x >> 2;
    const int ln = threadIdx.x & 63;   // lane = query owner
    // force wave id uniform so the candidate address scalarizes to s_load
    const int wvu = __builtin_amdgcn_readfirstlane((int)(threadIdx.x >> 6));
    const int q  = bq * QB + ln;

    const float px = pos1[q * 3 + 0];
    const float py = pos1[q * 3 + 1];
    const float pz = pos1[q * 3 + 2];
    const float nx = -px, ny = -py, nz = -pz;
    const float hp = 0.5f * fmaf(px, px, fmaf(py, py, pz * pz));

    const int jb = piece * PCE + wvu * SLCW;
    const float4* cp = pos2pk + jb;

    const float KINIT = __uint_as_float(0x7F000000u);   // large finite sentinel
    float k0 = KINIT, k1 = KINIT, k2 = KINIT;

#define LOADG(v0, v1, v2, v3, g) { v0 = cp[(g)*4+0]; v1 = cp[(g)*4+1]; \
                                   v2 = cp[(g)*4+2]; v3 = cp[(g)*4+3]; }
#define CONSG(v0, v1, v2, v3, g) { const unsigned j0 = (unsigned)(jb + (g)*4); \
        ins3(k0, k1, k2, mkk(nx, ny, nz, hp, v0, j0 + 0)); \
        ins3(k0, k1, k2, mkk(nx, ny, nz, hp, v1, j0 + 1)); \
        ins3(k0, k1, k2, mkk(nx, ny, nz, hp, v2, j0 + 2)); \
        ins3(k0, k1, k2, mkk(nx, ny, nz, hp, v3, j0 + 3)); }

    float4 A0, A1, A2, A3, B0, B1, B2, B3;
    LOADG(A0, A1, A2, A3, 0);
    for (int g = 0; g < NG; g += 2) {
        LOADG(B0, B1, B2, B3, g + 1);   // prefetch next while A in flight/consumed
        CONSG(A0, A1, A2, A3, g);
        LOADG(A0, A1, A2, A3, g + 2);   // g+2 == NG overshoots into the pad (read-only)
        CONSG(B0, B1, B2, B3, g + 1);
    }
#undef LOADG
#undef CONSG

    skl[ln][wvu * 3 + 0] = __float_as_uint(k0);
    skl[ln][wvu * 3 + 1] = __float_as_uint(k1);
    skl[ln][wvu * 3 + 2] = __float_as_uint(k2);
    __syncthreads();

    // coalesced dump: query q's survivors at skeys[q*48 + piece*12 + slot]
    {
        const int ql = threadIdx.x >> 2;
        const int sp = (threadIdx.x & 3) * 3;
        unsigned* dst = &skeys[(size_t)(bq * QB + ql) * NSURV + piece * 12 + sp];
        dst[0] = skl[ql][sp + 0];
        dst[1] = skl[ql][sp + 1];
        dst[2] = skl[ql][sp + 2];
    }
}

// ---------------------------------------------------------------------------
// bf16-MFMA fused layer GEMM: Y = Xin @ W^T + bias (fp32 accumulate).
//   MODE 0: prologue re-ranks this block's own 64 queries (fp64 exact) from
//           skeys, then Xin = interp(feat2(fp32), idx, w). Y out: bf16.
//   MODE 1: prologue reduces statsIn[8][256] -> BN scale/shift in LDS, then
//           Xin = relu(Xbf16 * sc[c] + sh[c]). Y out: bf16.
// Y is stored bf16 (halves inter-layer HBM traffic; next stage re-rounds to
// bf16 anyway, extra error ~2e-3/layer). Stats stay fp32 from accumulators.
// Epilogue stats -> 8-group atomicAdd (2048 addresses, zeroed by knn prep).
// grid = 512, block = 256.
// ---------------------------------------------------------------------------
template <int MODE>
__global__ __launch_bounds__(256) void gemm_mfma(const void* __restrict__ Xsrc_,
                                                 const unsigned* __restrict__ skeys,
                                                 const float* __restrict__ pos1,
                                                 const float* __restrict__ pos2,
                                                 const float* __restrict__ statsIn,
                                                 const float* __restrict__ gIn,
                                                 const float* __restrict__ beIn,
                                                 const ushort_t* __restrict__ Wb,
                                                 const float* __restrict__ bias,
                                                 ushort_t* __restrict__ Y,
                                                 float* __restrict__ statsOut) {
    __shared__ __align__(16) short xa[64][136];    // 64 rows x 128 k bf16
    __shared__ __align__(16) short wb[128][136];   // 128 co x 128 k bf16
    __shared__ float blk_s[CC], blk_q[CC];         // epilogue stat accumulators
    __shared__ float sc_l[CC], sh_l[CC];           // MODE 1 BN scale/shift

    const int row0 = blockIdx.x * 64;

    // ---- X tile staging (+ fused transform) ----
    if constexpr (MODE == 0) {
        const float* feat2 = (const float*)Xsrc_;
        __shared__ int   lidx[QB][3];
        __shared__ float lw[QB][3];
        {   // exact fp64 re-rank of this block's 64 queries; 4 thr/query
            double* rrd = (double*)&xa[0][0];   // [64][4][3] = 6144 B scratch
            int*    rri = (int*)&wb[0][0];      // [64][4][3] = 3072 B scratch
            const int ql = threadIdx.x >> 2;
            const int pp = threadIdx.x & 3;
            const int qg = row0 + ql;
            const double qx = (double)pos1[qg * 3 + 0];
            const double qy = (double)pos1[qg * 3 + 1];
            const double qz = (double)pos1[qg * 3 + 2];
            double b0 = DBL_BIG, b1 = DBL_BIG, b2 = DBL_BIG;
            int    j0 = IDX_BIG, j1 = IDX_BIG, j2 = IDX_BIG;
            const uint4* kp = (const uint4*)(skeys + (size_t)qg * NSURV + pp * 12);
#pragma unroll
            for (int gi = 0; gi < 3; ++gi) {
                const uint4 kk = kp[gi];
                const unsigned ks[4] = {kk.x, kk.y, kk.z, kk.w};
#pragma unroll
                for (int u = 0; u < 4; ++u) {
                    const int id = (int)(ks[u] & IMASK);
                    const double x = (double)pos2[id * 3 + 0];
                    const double y = (double)pos2[id * 3 + 1];
                    const double z = (double)pos2[id * 3 + 2];
                    const double ax = qx - x, ay = qy - y, az = qz - z;
                    const double d = ax * ax + ay * ay + az * az;
                    const bool l2 = (d < b2) || (d == b2 && id < j2);
                    if (l2) {
                        const bool l1 = (d < b1) || (d == b1 && id < j1);
                        const bool l0 = (d < b0) || (d == b0 && id < j0);
                        b2 = l1 ? b1 : d;              j2 = l1 ? j1 : id;
                        b1 = l1 ? (l0 ? b0 : d) : b1;  j1 = l1 ? (l0 ? j0 : id) : j1;
                        b0 = l0 ? d : b0;              j0 = l0 ? id : j0;
                    }
                }
            }
            const int base = (ql * 4 + pp) * 3;
            rrd[base + 0] = b0; rri[base + 0] = j0;
            rrd[base + 1] = b1; rri[base + 1] = j1;
            rrd[base + 2] = b2; rri[base + 2] = j2;
            __syncthreads();
            if (threadIdx.x < QB) {
                const int qq = threadIdx.x;
                double c0 = DBL_BIG, c1 = DBL_BIG, c2 = DBL_BIG;
                int    i0 = IDX_BIG, i1 = IDX_BIG, i2 = IDX_BIG;
#pragma unroll
                for (int s = 0; s < 12; ++s) {
                    const double d = rrd[qq * 12 + s];
                    const int   id = rri[qq * 12 + s];
                    const bool l2 = (d < c2) || (d == c2 && id < i2);
                    if (l2) {
                        const bool l1 = (d < c1) || (d == c1 && id < i1);
                        const bool l0 = (d < c0) || (d == c0 && id < i0);
                        c2 = l1 ? c1 : d;              i2 = l1 ? i1 : id;
                        c1 = l1 ? (l0 ? c0 : d) : c1;  i1 = l1 ? (l0 ? i0 : id) : i1;
                        c0 = l0 ? d : c0;              i0 = l0 ? id : i0;
                    }
                }
                const double r0 = 1.0 / (c0 + EPS_D);
                const double r1 = 1.0 / (c1 + EPS_D);
                const double r2 = 1.0 / (c2 + EPS_D);
                const double inv = 1.0 / (r0 + r1 + r2);
                lidx[qq][0] = i0; lidx[qq][1] = i1; lidx[qq][2] = i2;
                lw[qq][0] = (float)(r0 * inv);
                lw[qq][1] = (float)(r1 * inv);
                lw[qq][2] = (float)(r2 * inv);
            }
            __syncthreads();
        }
        if (threadIdx.x < CC) { blk_s[threadIdx.x] = 0.f; blk_q[threadIdx.x] = 0.f; }
#pragma unroll
        for (int e = threadIdx.x; e < 64 * 32; e += 256) {
            const int r = e >> 5, c4 = e & 31;
            const int i0 = lidx[r][0], i1 = lidx[r][1], i2 = lidx[r][2];
            const float w0 = lw[r][0], w1 = lw[r][1], w2 = lw[r][2];
            const float4 f0 = *(const float4*)&feat2[(size_t)i0 * CC + c4 * 4];
            const float4 f1 = *(const float4*)&feat2[(size_t)i1 * CC + c4 * 4];
            const float4 f2 = *(const float4*)&feat2[(size_t)i2 * CC + c4 * 4];
            float4 v;
            v.x = w0 * f0.x + w1 * f1.x + w2 * f2.x;
            v.y = w0 * f0.y + w1 * f1.y + w2 * f2.y;
            v.z = w0 * f0.z + w1 * f1.z + w2 * f2.z;
            v.w = w0 * f0.w + w1 * f1.w + w2 * f2.w;
            unsigned* dst = (unsigned*)&xa[r][0];
            dst[c4 * 2 + 0] = bf16pair(v.x, v.y);
            dst[c4 * 2 + 1] = bf16pair(v.z, v.w);
        }
    } else {
        const ushort_t* Xbf = (const ushort_t*)Xsrc_;
        // ---- BN prologue: reduce 8-group stats -> scale/shift in LDS ----
        if (threadIdx.x < CC) {
            const int c = threadIdx.x;
            float s = 0.f, q = 0.f;
#pragma unroll
            for (int gr = 0; gr < NGRP; ++gr) {
                s += statsIn[gr * 256 + c];
                q += statsIn[gr * 256 + CC + c];
            }
            const float m = s * (1.f / (float)NQ);
            const float v = fmaf(-m, m, q * (1.f / (float)NQ));
            const float rstd = rsqrtf(v + EPS_BN);
            const float scl = gIn[c] * rstd;
            sc_l[c] = scl;
            sh_l[c] = fmaf(-m, scl, beIn[c]);
            blk_s[c] = 0.f; blk_q[c] = 0.f;
        }
        __syncthreads();
        // X staging: uint4 = 8 bf16 per iter, 4 iters/thread
#pragma unroll
        for (int e = threadIdx.x; e < 64 * 16; e += 256) {
            const int r = e >> 4, c8 = e & 15;
            const uint4 u = *(const uint4*)&Xbf[(size_t)(row0 + r) * CC + c8 * 8];
            const float4 s0 = *(const float4*)&sc_l[c8 * 8];
            const float4 s1 = *(const float4*)&sc_l[c8 * 8 + 4];
            const float4 h0 = *(const float4*)&sh_l[c8 * 8];
            const float4 h1 = *(const float4*)&sh_l[c8 * 8 + 4];
            const float v0 = fmaxf(fmaf(bflo(u.x), s0.x, h0.x), 0.f);
            const float v1 = fmaxf(fmaf(bfhi(u.x), s0.y, h0.y), 0.f);
            const float v2 = fmaxf(fmaf(bflo(u.y), s0.z, h0.z), 0.f);
            const float v3 = fmaxf(fmaf(bfhi(u.y), s0.w, h0.w), 0.f);
            const float v4 = fmaxf(fmaf(bflo(u.z), s1.x, h1.x), 0.f);
            const float v5 = fmaxf(fmaf(bfhi(u.z), s1.y, h1.y), 0.f);
            const float v6 = fmaxf(fmaf(bflo(u.w), s1.z, h1.z), 0.f);
            const float v7 = fmaxf(fmaf(bfhi(u.w), s1.w, h1.w), 0.f);
            uint4 o;
            o.x = bf16pair(v0, v1); o.y = bf16pair(v2, v3);
            o.z = bf16pair(v4, v5); o.w = bf16pair(v6, v7);
            *(uint4*)&xa[r][c8 * 8] = o;
        }
    }
    // ---- W tile staging: pre-converted bf16, 16B copies ----
#pragma unroll
    for (int e = threadIdx.x; e < 128 * 16; e += 256) {
        const int co = e >> 4, seg = e & 15;
        *(float4*)&wb[co][seg * 8] = *(const float4*)&Wb[(size_t)co * CC + seg * 8];
    }
    __syncthreads();

    const int lane = threadIdx.x & 63;
    const int wv = threadIdx.x >> 6;     // wave -> rows 16*wv..+15
    const int nn = lane & 15;
    const int quad = lane >> 4;

    floatx4 acc[8] = {};

    const short* arow = &xa[wv * 16 + nn][0];
#pragma unroll
    for (int ks = 0; ks < 4; ++ks) {
        const bf16x8 a = *(const bf16x8*)(arow + ks * 32 + quad * 8);
#pragma unroll
        for (int ct = 0; ct < 8; ++ct) {
            const bf16x8 b = *(const bf16x8*)(&wb[ct * 16 + nn][0] + ks * 32 + quad * 8);
            acc[ct] = __builtin_amdgcn_mfma_f32_16x16x32_bf16(a, b, acc[ct], 0, 0, 0);
        }
    }

    // ---- epilogue: bias, bf16 Y store, column stats (fp32) ----
#pragma unroll
    for (int ct = 0; ct < 8; ++ct) {
        const float bv = bias[ct * 16 + nn];
        float s = 0.f, qv = 0.f;
#pragma unroll
        for (int r = 0; r < 4; ++r) {
            acc[ct][r] += bv;
            s += acc[ct][r];
            qv = fmaf(acc[ct][r], acc[ct][r], qv);
        }
#pragma unroll
        for (int r = 0; r < 4; ++r)
            Y[(size_t)(row0 + wv * 16 + quad * 4 + r) * CC + ct * 16 + nn] = bf16one(acc[ct][r]);
        s += __shfl_xor(s, 16, 64); s += __shfl_xor(s, 32, 64);
        qv += __shfl_xor(qv, 16, 64); qv += __shfl_xor(qv, 32, 64);
        if (quad == 0) {
            atomicAdd(&blk_s[ct * 16 + nn], s);
            atomicAdd(&blk_q[ct * 16 + nn], qv);
        }
    }
    __syncthreads();
    // 8-group global stats: low-contention atomicAdd (2048 addresses)
    {
        const int ch = threadIdx.x;
        const float v = (ch < CC) ? blk_s[ch] : blk_q[ch - CC];
        atomicAdd(&statsOut[(blockIdx.x & (NGRP - 1)) * 256 + ch], v);
    }
}

// ---------------------------------------------------------------------------
// Final BN + ReLU with in-kernel stats reduce; bf16 in, fp32 out.
// grid = 512 x 256; each thread handles 4 x 8 elements.
// ---------------------------------------------------------------------------
__global__ __launch_bounds__(256) void bn_final(const ushort_t* __restrict__ Y,
                                                const float* __restrict__ statsIn,
                                                const float* __restrict__ g,
                                                const float* __restrict__ be,
                                                float* __restrict__ out) {
    __shared__ float sc_l[CC], sh_l[CC];
    if (threadIdx.x < CC) {
        const int c = threadIdx.x;
        float s = 0.f, q = 0.f;
#pragma unroll
        for (int gr = 0; gr < NGRP; ++gr) {
            s += statsIn[gr * 256 + c];
            q += statsIn[gr * 256 + CC + c];
        }
        const float m = s * (1.f / (float)NQ);
        const float v = fmaf(-m, m, q * (1.f / (float)NQ));
        const float rstd = rsqrtf(v + EPS_BN);
        const float scl = g[c] * rstd;
        sc_l[c] = scl;
        sh_l[c] = fmaf(-m, scl, be[c]);
    }
    __syncthreads();
    const int base = blockIdx.x * 1024 + threadIdx.x;   // 8-col group index
#pragma unroll
    for (int it = 0; it < 4; ++it) {
        const int i8 = base + it * 256;
        const int c8 = (i8 & 15) * 8;
        const uint4 u = *(const uint4*)&Y[(size_t)i8 * 8];
        const float4 s0 = *(const float4*)&sc_l[c8];
        const float4 s1 = *(const float4*)&sc_l[c8 + 4];
        const float4 h0 = *(const float4*)&sh_l[c8];
        const float4 h1 = *(const float4*)&sh_l[c8 + 4];
        float4 o0, o1;
        o0.x = fmaxf(fmaf(bflo(u.x), s0.x, h0.x), 0.f);
        o0.y = fmaxf(fmaf(bfhi(u.x), s0.y, h0.y), 0.f);
        o0.z = fmaxf(fmaf(bflo(u.y), s0.z, h0.z), 0.f);
        o0.w = fmaxf(fmaf(bfhi(u.y), s0.w, h0.w), 0.f);
        o1.x = fmaxf(fmaf(bflo(u.z), s1.x, h1.x), 0.f);
        o1.y = fmaxf(fmaf(bfhi(u.z), s1.y, h1.y), 0.f);
        o1.z = fmaxf(fmaf(bflo(u.w), s1.z, h1.z), 0.f);
        o1.w = fmaxf(fmaf(bfhi(u.w), s1.w, h1.w), 0.f);
        ((float4*)out)[i8 * 2 + 0] = o0;
        ((float4*)out)[i8 * 2 + 1] = o1;
    }
}

// ---------------------------------------------------------------------------
extern "C" void kernel_launch(void* const* d_in, const int* in_sizes, int n_in,
                              void* d_out, int out_size, void* d_ws, size_t ws_size,
                              hipStream_t stream) {
    (void)in_sizes; (void)n_in; (void)out_size; (void)ws_size;

    const float* pos1  = (const float*)d_in[0];
    const float* pos2  = (const float*)d_in[1];
    const float* feat2 = (const float*)d_in[2];
    const float* Wl[3]  = {(const float*)d_in[3], (const float*)d_in[7],  (const float*)d_in[11]};
    const float* bl[3]  = {(const float*)d_in[4], (const float*)d_in[8],  (const float*)d_in[12]};
    const float* gl[3]  = {(const float*)d_in[5], (const float*)d_in[9],  (const float*)d_in[13]};
    const float* bel[3] = {(const float*)d_in[6], (const float*)d_in[10], (const float*)d_in[14]};

    // Workspace layout
    float* ws = (float*)d_ws;
    ushort_t* B0 = (ushort_t*)ws;                   // NQ*CC bf16 (8 MB)
    ushort_t* B1 = B0 + (size_t)NQ * CC;            // NQ*CC bf16 (8 MB)
    unsigned* skeys = (unsigned*)(B1 + (size_t)NQ * CC);   // NQ*48 u32 (6 MB)
    float* stats = (float*)(skeys + (size_t)NQ * NSURV);   // 3*NGRP*256 floats
    ushort_t* Wbf = (ushort_t*)(stats + 3 * NGRP * 256);   // 3*16384 bf16
    float4* pos2pk = (float4*)(Wbf + 3 * CC * CC);         // (MC+4)*16 B

    float* st0 = stats + 0 * NGRP * 256;
    float* st1 = stats + 1 * NGRP * 256;
    float* st2 = stats + 2 * NGRP * 256;

    // 0: pack pos2 -> {x,y,z,0.5|c|^2} (+pad; must precede knn scan)
    pack_kernel<<<8, TB, 0, stream>>>(pos2, pos2pk);
    // 1: KNN scan (pipelined SGPR candidate stream) + W bf16 prep + stats zero
    knn_kernel<<<KNN_B + 16, TB, 0, stream>>>(pos1, pos2pk, skeys,
                                              Wl[0], Wl[1], Wl[2], Wbf, stats);
    // 2: layer 0 (rerank + interp fused) -> B0 (bf16), st0
    gemm_mfma<0><<<GEMM_B, 256, 0, stream>>>(feat2, skeys, pos1, pos2,
                                             nullptr, nullptr, nullptr,
                                             Wbf + 0 * CC * CC, bl[0], B0, st0);
    // 3: layer 1 (stats-reduce + BN fused) -> B1 (bf16), st1
    gemm_mfma<1><<<GEMM_B, 256, 0, stream>>>(B0, nullptr, nullptr, nullptr,
                                             st0, gl[0], bel[0],
                                             Wbf + 1 * CC * CC, bl[1], B1, st1);
    // 4: layer 2 -> B0 (bf16), st2
    gemm_mfma<1><<<GEMM_B, 256, 0, stream>>>(B1, nullptr, nullptr, nullptr,
                                             st1, gl[1], bel[1],
                                             Wbf + 2 * CC * CC, bl[2], B0, st2);
    // 5: final BN+ReLU (stats-reduce fused) -> out (fp32)
    bn_final<<<GEMM_B, 256, 0, stream>>>(B0, st2, gl[2], bel[2], (float*)d_out);
}